// Round 9
// baseline (300.509 us; speedup 1.0000x reference)
//
#include <hip/hip_runtime.h>
#include <hip/hip_bf16.h>

#define N_NODES 5000
#define N_EDGES 80000
#define HID_DIM 128
#define OUT_DIM 64
#define BATCH 8
#define M_ROWS 40000
#define NEG_SLOPE 0.2f
#define BUCKET 96   // fixed per-node capacity; deg~Poisson(16), P(>96)~0 (+20 sigma)

// R9: TRUE 3-enqueue pipeline (R8 kept 4 slots: memset+3 kernels -> measured only
// the inline-pack penalty +3.5us). Scatter no longer needs pre-zeroed global cnt:
// blocks 0..19 of gemm_fused own 250 dst-nodes each, zero counters in LDS (overlaid
// on the z1-tile buffer), scan e_dst (320KB, L2-hot), bucket owned edges via LDS
// atomics, write cnt once. Block 20 computes cb/cmeta. W-pack per-block in LDS
// (R8-calibrated cost). agg_mid/agg_fin byte-identical to R6 (proven).
// Enqueues: gemm_fused + agg_mid + agg_fin = 3.

typedef unsigned short ushort_t;
typedef unsigned int uint_t;
typedef __attribute__((ext_vector_type(8))) short short8;  // 8 bf16 = 4 VGPRs
typedef __attribute__((ext_vector_type(4))) float f32x4;

__device__ __forceinline__ float bf16_to_f32(ushort_t u) {
  return __uint_as_float(((uint_t)u) << 16);
}
__device__ __forceinline__ ushort_t f32_to_bf16(float f) {
  uint_t u = __float_as_uint(f);
  return (ushort_t)((u + 0x7FFF + ((u >> 16) & 1)) >> 16);  // RNE
}

// ws layout (R9 == R8)
#define OFF_CMETA 49152u      // 2 floats (cl2, cr2)
#define OFF_CB    49184u      // 64 floats (c + b2)
#define OFF_Y     65536u      // 40000*64 bf16 = 5.12 MB
#define OFF_EY    5185536u    // 40000 float2 = 320 KB
#define OFF_W     5505536u    // 40000*64 bf16 = 5.12 MB
#define OFF_EL1   10625536u
#define OFF_ER1   10785536u
#define OFF_EL2   10945536u
#define OFF_ER2   11105536u
#define OFF_CNT   11265536u   // 5000 ints (written directly by scatter owners)
#define OFF_SRCS  11285536u   // 5000*96 ints, ends 13,205,536

#define NODES_PER_OWNER 250   // 20 owner blocks x 250 = 5000

// ---------------- fused gemm: pack W (LDS) + owned-range scatter + x@W1 -> @W2 = y --------
__global__ __launch_bounds__(256) void gemm_fused(const float* __restrict__ A,
                                                  const float* __restrict__ W1,
                                                  const float* __restrict__ W2,
                                                  const float* __restrict__ b1,
                                                  const float* __restrict__ b2,
                                                  const float* __restrict__ al1,
                                                  const float* __restrict__ ar1,
                                                  const float* __restrict__ al2,
                                                  const float* __restrict__ ar2,
                                                  float* __restrict__ el1,
                                                  float* __restrict__ er1,
                                                  ushort_t* __restrict__ y,
                                                  float2* __restrict__ ey,
                                                  const int* __restrict__ e_src,
                                                  const int* __restrict__ e_dst,
                                                  int* __restrict__ cnt,
                                                  int* __restrict__ srcs,
                                                  float* __restrict__ cmeta,
                                                  float* __restrict__ cb) {
  __shared__ ushort_t ldsB1[2048 * 8];   // 32 KB: W1 fragments
  __shared__ ushort_t ldsB2[1024 * 8];   // 16 KB: W2 fragments
  __shared__ ushort_t lds[64 * 128];     // 16 KB: z1 tile; first 1KB doubles as scatter counters
  int* cnt_lds = (int*)lds;
  int tid = threadIdx.x, bid = blockIdx.x;
  int wave = tid >> 6, lane = tid & 63;
  int q = lane >> 4, m = lane & 15;
  int r0 = bid * 64 + wave * 16;

  // ---- prologue A: pack W1/W2 -> LDS fragments (all blocks; R8-calibrated) ----
  for (int it = 0; it < 12; it++) {
    int gid = it * 256 + tid;  // 0..3071
    const float* W; ushort_t* Bp; int NC, idx;
    if (gid < 2048) { W = W1; Bp = ldsB1; NC = 128; idx = gid; }
    else            { W = W2; Bp = ldsB2; NC = 64;  idx = gid - 2048; }
    int l = idx & 63, tt = idx >> 6;
    int T = NC / 16;
    int kc = tt / T, t = tt % T;
    int col = t * 16 + (l & 15);
    int krow = kc * 32 + (l >> 4) * 8;
    short8 vv;
#pragma unroll
    for (int j = 0; j < 8; j++) vv[j] = (short)f32_to_bf16(W[(size_t)(krow + j) * NC + col]);
    *(short8*)(Bp + (size_t)idx * 8) = vv;
  }

  // ---- prologue B (blocks 0..19): owned-range edge scatter, LDS counters ----
  if (bid < 20) {
    int base = bid * NODES_PER_OWNER;
    if (tid < NODES_PER_OWNER) cnt_lds[tid] = 0;
    __syncthreads();
    for (int j = tid; j < N_EDGES; j += 256) {
      int d = e_dst[j];
      int s = e_src[j];
      int rel = d - base;
      if ((unsigned)rel < (unsigned)NODES_PER_OWNER) {
        int pos = atomicAdd(&cnt_lds[rel], 1);
        if (pos < BUCKET) srcs[d * BUCKET + pos] = s;  // clamp: structurally safe
      }
    }
    __syncthreads();
    if (tid < NODES_PER_OWNER) cnt[base + tid] = cnt_lds[tid];
    // cnt_lds reads complete before the unconditional barrier below; z1-tile
    // writes (which overwrite this region) happen after that barrier.
  }

  // ---- prologue C (block 20): cb = b1@W2 + b2 ; cmeta = (c·al2, c·ar2) sums ----
  if (bid == 20 && tid < 64) {
    int f = tid;
    float c = 0.f;
#pragma unroll 8
    for (int k = 0; k < 128; k++) c += b1[k] * W2[(size_t)k * 64 + f];
    cb[f] = c + b2[f];
    float cl = c * al2[f], cr = c * ar2[f];
#pragma unroll
    for (int o = 32; o; o >>= 1) {
      cl += __shfl_xor(cl, o, 64);
      cr += __shfl_xor(cr, o, 64);
    }
    if (f == 0) { cmeta[0] = cl; cmeta[1] = cr; }
  }
  __syncthreads();  // pack + scatter-LDS-reads complete before GEMM/z1 writes

  // ---- stage 1: z1_tile = x_tile @ W1 (T=8) ----
  f32x4 acc[8];
#pragma unroll
  for (int t = 0; t < 8; t++)
#pragma unroll
    for (int i = 0; i < 4; i++) acc[t][i] = 0.f;
  const short8* B1 = (const short8*)ldsB1;
  size_t arow = (size_t)(r0 + m) * 128;
#pragma unroll
  for (int kc = 0; kc < 4; kc++) {
    const float* Ap = A + arow + kc * 32 + q * 8;
    float4 v0 = *(const float4*)Ap;
    float4 v1 = *(const float4*)(Ap + 4);
    short8 af;
    af[0] = (short)f32_to_bf16(v0.x); af[1] = (short)f32_to_bf16(v0.y);
    af[2] = (short)f32_to_bf16(v0.z); af[3] = (short)f32_to_bf16(v0.w);
    af[4] = (short)f32_to_bf16(v1.x); af[5] = (short)f32_to_bf16(v1.y);
    af[6] = (short)f32_to_bf16(v1.z); af[7] = (short)f32_to_bf16(v1.w);
#pragma unroll
    for (int t = 0; t < 8; t++)
      acc[t] = __builtin_amdgcn_mfma_f32_16x16x32_bf16(af, B1[(kc * 8 + t) * 64 + lane], acc[t], 0, 0, 0);
  }
  // el1/er1 epilogue (fp32 acc, reduce over 16 m-lanes) — proven pattern
  {
    float sl[4] = {0.f, 0.f, 0.f, 0.f}, sr[4] = {0.f, 0.f, 0.f, 0.f};
#pragma unroll
    for (int t = 0; t < 8; t++) {
      float alv = al1[t * 16 + m], arv = ar1[t * 16 + m];
#pragma unroll
      for (int i = 0; i < 4; i++) { sl[i] += acc[t][i] * alv; sr[i] += acc[t][i] * arv; }
    }
#pragma unroll
    for (int o = 1; o < 16; o <<= 1)
#pragma unroll
      for (int i = 0; i < 4; i++) {
        sl[i] += __shfl_xor(sl[i], o, 64);
        sr[i] += __shfl_xor(sr[i], o, 64);
      }
    if (m == 0)
#pragma unroll
      for (int i = 0; i < 4; i++) {
        el1[r0 + q * 4 + i] = sl[i];
        er1[r0 + q * 4 + i] = sr[i];
      }
  }
  // stage-1 -> LDS (bf16, RNE): row = q*4+i+wave*16, col = t*16+m; byte ^= (row&7)<<4
#pragma unroll
  for (int t = 0; t < 8; t++)
#pragma unroll
    for (int i = 0; i < 4; i++) {
      int row = q * 4 + i + wave * 16;
      int byte = row * 256 + (t * 16 + m) * 2;
      lds[(byte ^ ((row & 7) << 4)) >> 1] = f32_to_bf16(acc[t][i]);
    }
  __syncthreads();

  // ---- stage 2: y_tile = z1_tile(bf16) @ W2 (T=4) ----
  f32x4 acc2[4];
#pragma unroll
  for (int t = 0; t < 4; t++)
#pragma unroll
    for (int i = 0; i < 4; i++) acc2[t][i] = 0.f;
  const short8* B2 = (const short8*)ldsB2;
  int row2 = wave * 16 + m;
#pragma unroll
  for (int kc = 0; kc < 4; kc++) {
    int byte = row2 * 256 + kc * 64 + q * 16;      // 16B-aligned; XOR keeps bits 0-3
    short8 af2 = *(const short8*)((const char*)lds + (byte ^ ((row2 & 7) << 4)));
#pragma unroll
    for (int t = 0; t < 4; t++)
      acc2[t] = __builtin_amdgcn_mfma_f32_16x16x32_bf16(af2, B2[(kc * 4 + t) * 64 + lane], acc2[t], 0, 0, 0);
  }
  // ey epilogue (y·al2, y·ar2 per row, fp32 pre-rounding)
  {
    float sl[4] = {0.f, 0.f, 0.f, 0.f}, sr[4] = {0.f, 0.f, 0.f, 0.f};
#pragma unroll
    for (int t = 0; t < 4; t++) {
      float alv = al2[t * 16 + m], arv = ar2[t * 16 + m];
#pragma unroll
      for (int i = 0; i < 4; i++) { sl[i] += acc2[t][i] * alv; sr[i] += acc2[t][i] * arv; }
    }
#pragma unroll
    for (int o = 1; o < 16; o <<= 1)
#pragma unroll
      for (int i = 0; i < 4; i++) {
        sl[i] += __shfl_xor(sl[i], o, 64);
        sr[i] += __shfl_xor(sr[i], o, 64);
      }
    if (m == 0)
#pragma unroll
      for (int i = 0; i < 4; i++) ey[r0 + q * 4 + i] = make_float2(sl[i], sr[i]);
  }
  // y store: row = r0 + q*4 + i, col = t*16 + m (m89-verified layout)
#pragma unroll
  for (int t = 0; t < 4; t++)
#pragma unroll
    for (int i = 0; i < 4; i++)
      y[(size_t)(r0 + q * 4 + i) * 64 + t * 16 + m] = f32_to_bf16(acc2[t][i]);
}

// ---------------- mid aggregation: w = A1·y ; el2/er2 = A1·ey + c·a (scalars) ----------
__global__ __launch_bounds__(256) void agg_mid(const ushort_t* __restrict__ y,
                                               const float2* __restrict__ ey,
                                               const float* __restrict__ el,
                                               const float* __restrict__ er,
                                               const int* __restrict__ cnt,
                                               const int* __restrict__ srcs,
                                               const float* __restrict__ cmeta,
                                               ushort_t* __restrict__ w,
                                               float* __restrict__ el2,
                                               float* __restrict__ er2) {
  int id = (threadIdx.x >> 6) * gridDim.x + blockIdx.x;  // gridDim%8==0: batch=XCD pairing
  int lane = threadIdx.x & 63;
  int g = lane >> 4, l16 = lane & 15;
  int b = id & 7, n = id >> 3;
  int deg = cnt[n]; if (deg > BUCKET) deg = BUCKET;
  int off0 = n * BUCKET;
  int rbase = b * N_NODES;
  float er_n = er[rbase + n];

  float acc[4] = {0.f, 0.f, 0.f, 0.f};
  float lsum = 0.f, sl2 = 0.f, sr2 = 0.f;

  for (int c = 0; c < deg; c += 64) {
    int j = c + lane;
    int s_my = 0;
    float w_my = 0.f;
    if (j < deg) {
      s_my = srcs[off0 + j];
      float e = el[rbase + s_my] + er_n;
      e = e > 0.f ? e : NEG_SLOPE * e;
      w_my = __expf(e);
      lsum += w_my;
      float2 ev = ey[rbase + s_my];
      sl2 += w_my * ev.x;
      sr2 += w_my * ev.y;
    }
    int cl = deg - c; if (cl > 64) cl = 64;
    for (int k0 = 0; k0 < cl; k0 += 16) {   // R5 4x-unrolled gather (MLP=4)
      float wk[4]; int sk[4];
#pragma unroll
      for (int u = 0; u < 4; u++) {
        int e_idx = k0 + u * 4 + g;
        wk[u] = __shfl(w_my, e_idx, 64);
        sk[u] = __shfl(s_my, e_idx, 64);
      }
      uint2 zw[4];
#pragma unroll
      for (int u = 0; u < 4; u++)
        zw[u] = *(const uint2*)(y + (size_t)(rbase + sk[u]) * 64 + l16 * 4);
#pragma unroll
      for (int u = 0; u < 4; u++) {
        acc[0] += wk[u] * bf16_to_f32((ushort_t)(zw[u].x & 0xFFFF));
        acc[1] += wk[u] * bf16_to_f32((ushort_t)(zw[u].x >> 16));
        acc[2] += wk[u] * bf16_to_f32((ushort_t)(zw[u].y & 0xFFFF));
        acc[3] += wk[u] * bf16_to_f32((ushort_t)(zw[u].y >> 16));
      }
    }
  }
#pragma unroll
  for (int j = 0; j < 4; j++) {
    acc[j] += __shfl_xor(acc[j], 16, 64);
    acc[j] += __shfl_xor(acc[j], 32, 64);
  }
  float sum = lsum;
#pragma unroll
  for (int o = 32; o; o >>= 1) {
    sum += __shfl_xor(sum, o, 64);
    sl2 += __shfl_xor(sl2, o, 64);
    sr2 += __shfl_xor(sr2, o, 64);
  }
  float inv = (deg > 0) ? 1.f / sum : 0.f;

  if (g == 0) {
    uint_t pk0 = (uint_t)f32_to_bf16(acc[0] * inv) | ((uint_t)f32_to_bf16(acc[1] * inv) << 16);
    uint_t pk1 = (uint_t)f32_to_bf16(acc[2] * inv) | ((uint_t)f32_to_bf16(acc[3] * inv) << 16);
    *(uint2*)(w + (size_t)(rbase + n) * 64 + l16 * 4) = make_uint2(pk0, pk1);
  }
  if (lane == 0) {
    el2[rbase + n] = sl2 * inv + cmeta[0];
    er2[rbase + n] = sr2 * inv + cmeta[1];
  }
}

// ---------------- final aggregation: o = A2·w + cb, row softmax -> fp32 out ----------
__global__ __launch_bounds__(256) void agg_fin(const ushort_t* __restrict__ w,
                                               const float* __restrict__ el,
                                               const float* __restrict__ er,
                                               const float* __restrict__ cb,
                                               const int* __restrict__ cnt,
                                               const int* __restrict__ srcs,
                                               float* __restrict__ outp) {
  int id = (threadIdx.x >> 6) * gridDim.x + blockIdx.x;
  int lane = threadIdx.x & 63;
  int g = lane >> 4, l16 = lane & 15;
  int b = id & 7, n = id >> 3;
  int deg = cnt[n]; if (deg > BUCKET) deg = BUCKET;
  int off0 = n * BUCKET;
  int rbase = b * N_NODES;
  float er_n = er[rbase + n];

  float acc[4] = {0.f, 0.f, 0.f, 0.f};
  float lsum = 0.f;

  for (int c = 0; c < deg; c += 64) {
    int j = c + lane;
    int s_my = 0;
    float w_my = 0.f;
    if (j < deg) {
      s_my = srcs[off0 + j];
      float e = el[rbase + s_my] + er_n;
      e = e > 0.f ? e : NEG_SLOPE * e;
      w_my = __expf(e);
      lsum += w_my;
    }
    int cl = deg - c; if (cl > 64) cl = 64;
    for (int k0 = 0; k0 < cl; k0 += 16) {
      float wk[4]; int sk[4];
#pragma unroll
      for (int u = 0; u < 4; u++) {
        int e_idx = k0 + u * 4 + g;
        wk[u] = __shfl(w_my, e_idx, 64);
        sk[u] = __shfl(s_my, e_idx, 64);
      }
      uint2 zw[4];
#pragma unroll
      for (int u = 0; u < 4; u++)
        zw[u] = *(const uint2*)(w + (size_t)(rbase + sk[u]) * 64 + l16 * 4);
#pragma unroll
      for (int u = 0; u < 4; u++) {
        acc[0] += wk[u] * bf16_to_f32((ushort_t)(zw[u].x & 0xFFFF));
        acc[1] += wk[u] * bf16_to_f32((ushort_t)(zw[u].x >> 16));
        acc[2] += wk[u] * bf16_to_f32((ushort_t)(zw[u].y & 0xFFFF));
        acc[3] += wk[u] * bf16_to_f32((ushort_t)(zw[u].y >> 16));
      }
    }
  }
#pragma unroll
  for (int j = 0; j < 4; j++) {
    acc[j] += __shfl_xor(acc[j], 16, 64);
    acc[j] += __shfl_xor(acc[j], 32, 64);
  }
  float sum = lsum;
#pragma unroll
  for (int o = 32; o; o >>= 1) sum += __shfl_xor(sum, o, 64);
  float inv = (deg > 0) ? 1.f / sum : 0.f;

  float o[4];
#pragma unroll
  for (int j = 0; j < 4; j++) o[j] = acc[j] * inv + cb[l16 * 4 + j];
  float mm = fmaxf(fmaxf(o[0], o[1]), fmaxf(o[2], o[3]));
#pragma unroll
  for (int d = 1; d < 16; d <<= 1) mm = fmaxf(mm, __shfl_xor(mm, d, 64));
  float p0 = __expf(o[0] - mm), p1 = __expf(o[1] - mm);
  float p2 = __expf(o[2] - mm), p3 = __expf(o[3] - mm);
  float ss = p0 + p1 + p2 + p3;
#pragma unroll
  for (int d = 1; d < 16; d <<= 1) ss += __shfl_xor(ss, d, 64);
  if (g == 0) {
    float issv = 1.f / ss;
    *(float4*)(outp + (size_t)(rbase + n) * 64 + l16 * 4) =
        make_float4(p0 * issv, p1 * issv, p2 * issv, p3 * issv);
  }
}

extern "C" void kernel_launch(void* const* d_in, const int* in_sizes, int n_in,
                              void* d_out, int out_size, void* d_ws, size_t ws_size,
                              hipStream_t stream) {
  const float* x   = (const float*)d_in[0];
  const float* W1  = (const float*)d_in[1];
  const float* al1 = (const float*)d_in[2];
  const float* ar1 = (const float*)d_in[3];
  const float* b1  = (const float*)d_in[4];
  const float* W2  = (const float*)d_in[5];
  const float* al2 = (const float*)d_in[6];
  const float* ar2 = (const float*)d_in[7];
  const float* b2  = (const float*)d_in[8];
  const int* src = (const int*)d_in[9];
  const int* dst = (const int*)d_in[10];

  char* base = (char*)d_ws;
  float*    cmeta= (float*)(base + OFF_CMETA);
  float*    cb   = (float*)(base + OFF_CB);
  ushort_t* y    = (ushort_t*)(base + OFF_Y);
  float2*   ey   = (float2*)(base + OFF_EY);
  ushort_t* w    = (ushort_t*)(base + OFF_W);
  float* el1 = (float*)(base + OFF_EL1);
  float* er1 = (float*)(base + OFF_ER1);
  float* el2 = (float*)(base + OFF_EL2);
  float* er2 = (float*)(base + OFF_ER2);
  int* cnt  = (int*)(base + OFF_CNT);
  int* srcs = (int*)(base + OFF_SRCS);

  // 1) fused GEMM + W-pack(LDS) + owned-range scatter + cb/cmeta
  gemm_fused<<<M_ROWS / 64, 256, 0, stream>>>(x, W1, W2, b1, b2, al1, ar1, al2, ar2,
                                              el1, er1, y, ey, src, dst, cnt, srcs,
                                              cmeta, cb);

  // 2) mid aggregation: w = A1·y ; el2/er2
  agg_mid<<<M_ROWS / 4, 256, 0, stream>>>(y, ey, el1, er1, cnt, srcs, cmeta, w, el2, er2);

  // 3) final aggregation + row softmax
  agg_fin<<<M_ROWS / 4, 256, 0, stream>>>(w, el2, er2, cb, cnt, srcs, (float*)d_out);
}

// Round 11
// 142.753 us; speedup vs baseline: 2.1051x; 2.1051x over previous
//
#include <hip/hip_runtime.h>
#include <hip/hip_bf16.h>

#define N_NODES 5000
#define N_EDGES 80000
#define HID_DIM 128
#define OUT_DIM 64
#define BATCH 8
#define M_ROWS 40000
#define NEG_SLOPE 0.2f
#define BUCKET 96   // fixed per-node capacity; deg~Poisson(16), P(>96)~0 (+20 sigma)

// R11: R6 structure (best verified, 143.3us) + fel float4 pack from R10.
// R10 post-mortem: d_out-as-cnt crashed — graph REPLAYS don't re-zero d_out;
// stale floats-as-ints overflow atomicAdd -> negative pos -> OOB write -> abort.
// ws is also re-poisoned every replay (262MB fills in profile) -> no cross-launch
// state. True 3-enqueue refuted 3 ways (R8 memset+inline-pack, R9 owned-scan,
// R10 d_out scratch). 4 enqueues: setup + gemm_fused + agg_mid + agg_fin.
// fel = (el1, ey_l, ey_r, 0) per row: agg_mid weight phase does ONE 16B gather
// per edge instead of 4B(el1)+8B(ey).

typedef unsigned short ushort_t;
typedef unsigned int uint_t;
typedef __attribute__((ext_vector_type(8))) short short8;  // 8 bf16 = 4 VGPRs
typedef __attribute__((ext_vector_type(4))) float f32x4;

__device__ __forceinline__ float bf16_to_f32(ushort_t u) {
  return __uint_as_float(((uint_t)u) << 16);
}
__device__ __forceinline__ ushort_t f32_to_bf16(float f) {
  uint_t u = __float_as_uint(f);
  return (ushort_t)((u + 0x7FFF + ((u >> 16) & 1)) >> 16);  // RNE
}

// ws layout (R11)
#define OFF_BP1   0u          // 32 KB
#define OFF_BP2   32768u      // 16 KB
#define OFF_CMETA 49152u      // 2 floats (cl2, cr2)
#define OFF_CB    49184u      // 64 floats (c + b2)
#define OFF_FEL   65536u      // 40000 float4 (el1, ey_l, ey_r, pad) = 640 KB
#define OFF_Y     705536u     // 40000*64 bf16 = 5.12 MB
#define OFF_W     5825536u    // 40000*64 bf16 = 5.12 MB
#define OFF_ER1   10945536u   // 40000 floats
#define OFF_EL2   11105536u
#define OFF_ER2   11265536u
#define OFF_CNT   11425536u   // 5000 ints
#define OFF_SRCS  11445536u   // 5000*96 ints, ends 13,365,536

// ---------------- setup: zero cnt + pack W1/W2 + cb/cmeta (one dispatch, proven R6) -------
__global__ __launch_bounds__(256) void zero_pack_kernel(const float* __restrict__ W1,
                                                        const float* __restrict__ W2,
                                                        const float* __restrict__ b1,
                                                        const float* __restrict__ b2,
                                                        const float* __restrict__ al2,
                                                        const float* __restrict__ ar2,
                                                        int* __restrict__ cnt,
                                                        ushort_t* __restrict__ Bp1,
                                                        ushort_t* __restrict__ Bp2,
                                                        float* __restrict__ cmeta,
                                                        float* __restrict__ cb) {
  int bid = blockIdx.x;
  if (bid < 20) {
    int i = bid * 256 + threadIdx.x;
    if (i < N_NODES) cnt[i] = 0;
    return;
  }
  if (bid == 32) {
    int f = threadIdx.x;
    if (f < 64) {
      float c = 0.f;
#pragma unroll 8
      for (int k = 0; k < 128; k++) c += b1[k] * W2[(size_t)k * 64 + f];
      cb[f] = c + b2[f];
      float cl = c * al2[f], cr = c * ar2[f];
#pragma unroll
      for (int o = 32; o; o >>= 1) {
        cl += __shfl_xor(cl, o, 64);
        cr += __shfl_xor(cr, o, 64);
      }
      if (f == 0) { cmeta[0] = cl; cmeta[1] = cr; }
    }
    return;
  }
  int gid = (bid - 20) * 256 + threadIdx.x;  // 0..3071
  if (gid >= 3072) return;
  const float* W; ushort_t* Bp; int NC, idx;
  if (gid < 2048) { W = W1; Bp = Bp1; NC = 128; idx = gid; }
  else            { W = W2; Bp = Bp2; NC = 64;  idx = gid - 2048; }
  int l = idx & 63, tt = idx >> 6;
  int T = NC / 16;
  int kc = tt / T, t = tt % T;
  int col = t * 16 + (l & 15);
  int krow = kc * 32 + (l >> 4) * 8;
  short8 vv;
#pragma unroll
  for (int j = 0; j < 8; j++) vv[j] = (short)f32_to_bf16(W[(size_t)(krow + j) * NC + col]);
  *(short8*)(Bp + (size_t)idx * 8) = vv;
}

// ---------------- fused gemm: scatter + x@W1 (LDS) -> @W2 = y; fel pack epilogue ---------
__global__ __launch_bounds__(256) void gemm_fused(const float* __restrict__ A,
                                                  const ushort_t* __restrict__ Bp1,
                                                  const ushort_t* __restrict__ Bp2,
                                                  const float* __restrict__ al1,
                                                  const float* __restrict__ ar1,
                                                  const float* __restrict__ al2,
                                                  const float* __restrict__ ar2,
                                                  float* __restrict__ er1,
                                                  ushort_t* __restrict__ y,
                                                  float4* __restrict__ fel,
                                                  const int* __restrict__ e_src,
                                                  const int* __restrict__ e_dst,
                                                  int* __restrict__ cnt,
                                                  int* __restrict__ srcs) {
  // edge bucket-scatter prologue (gridDim=625 x 128 = 80000 exactly; proven form)
  if (threadIdx.x < 128) {
    int i = blockIdx.x * 128 + threadIdx.x;
    int d = e_dst[i];
    int pos = atomicAdd(&cnt[d], 1);
    if (pos < BUCKET) srcs[d * BUCKET + pos] = e_src[i];  // clamp: structurally safe
  }
  __shared__ ushort_t lds[64 * 128];  // 16 KB, z1 tile bf16, XOR-swizzled rows
  int wave = threadIdx.x >> 6, lane = threadIdx.x & 63;
  int q = lane >> 4, m = lane & 15;
  int r0 = blockIdx.x * 64 + wave * 16;

  // ---- stage 1: z1_tile = x_tile @ W1 (T=8) ----
  f32x4 acc[8];
#pragma unroll
  for (int t = 0; t < 8; t++)
#pragma unroll
    for (int i = 0; i < 4; i++) acc[t][i] = 0.f;
  const short8* B1 = (const short8*)Bp1;
  size_t arow = (size_t)(r0 + m) * 128;
#pragma unroll
  for (int kc = 0; kc < 4; kc++) {
    const float* Ap = A + arow + kc * 32 + q * 8;
    float4 v0 = *(const float4*)Ap;
    float4 v1 = *(const float4*)(Ap + 4);
    short8 af;
    af[0] = (short)f32_to_bf16(v0.x); af[1] = (short)f32_to_bf16(v0.y);
    af[2] = (short)f32_to_bf16(v0.z); af[3] = (short)f32_to_bf16(v0.w);
    af[4] = (short)f32_to_bf16(v1.x); af[5] = (short)f32_to_bf16(v1.y);
    af[6] = (short)f32_to_bf16(v1.z); af[7] = (short)f32_to_bf16(v1.w);
#pragma unroll
    for (int t = 0; t < 8; t++)
      acc[t] = __builtin_amdgcn_mfma_f32_16x16x32_bf16(af, B1[(kc * 8 + t) * 64 + lane], acc[t], 0, 0, 0);
  }
  // el1/er1 epilogue: keep el1 in regs for fel pack; store er1 (dense, per-node read)
  float el1v[4];
  {
    float sl[4] = {0.f, 0.f, 0.f, 0.f}, sr[4] = {0.f, 0.f, 0.f, 0.f};
#pragma unroll
    for (int t = 0; t < 8; t++) {
      float alv = al1[t * 16 + m], arv = ar1[t * 16 + m];
#pragma unroll
      for (int i = 0; i < 4; i++) { sl[i] += acc[t][i] * alv; sr[i] += acc[t][i] * arv; }
    }
#pragma unroll
    for (int o = 1; o < 16; o <<= 1)
#pragma unroll
      for (int i = 0; i < 4; i++) {
        sl[i] += __shfl_xor(sl[i], o, 64);
        sr[i] += __shfl_xor(sr[i], o, 64);
      }
#pragma unroll
    for (int i = 0; i < 4; i++) el1v[i] = sl[i];
    if (m == 0)
#pragma unroll
      for (int i = 0; i < 4; i++) er1[r0 + q * 4 + i] = sr[i];
  }
  // stage-1 -> LDS (bf16, RNE): row = q*4+i+wave*16, col = t*16+m; byte ^= (row&7)<<4
#pragma unroll
  for (int t = 0; t < 8; t++)
#pragma unroll
    for (int i = 0; i < 4; i++) {
      int row = q * 4 + i + wave * 16;
      int byte = row * 256 + (t * 16 + m) * 2;
      lds[(byte ^ ((row & 7) << 4)) >> 1] = f32_to_bf16(acc[t][i]);
    }
  __syncthreads();

  // ---- stage 2: y_tile = z1_tile(bf16) @ W2 (T=4) ----
  f32x4 acc2[4];
#pragma unroll
  for (int t = 0; t < 4; t++)
#pragma unroll
    for (int i = 0; i < 4; i++) acc2[t][i] = 0.f;
  const short8* B2 = (const short8*)Bp2;
  int row2 = wave * 16 + m;
#pragma unroll
  for (int kc = 0; kc < 4; kc++) {
    int byte = row2 * 256 + kc * 64 + q * 16;      // 16B-aligned; XOR keeps bits 0-3
    short8 af2 = *(const short8*)((const char*)lds + (byte ^ ((row2 & 7) << 4)));
#pragma unroll
    for (int t = 0; t < 4; t++)
      acc2[t] = __builtin_amdgcn_mfma_f32_16x16x32_bf16(af2, B2[(kc * 4 + t) * 64 + lane], acc2[t], 0, 0, 0);
  }
  // ey epilogue + fel pack: fel[row] = (el1, ey_l, ey_r, 0)
  {
    float sl[4] = {0.f, 0.f, 0.f, 0.f}, sr[4] = {0.f, 0.f, 0.f, 0.f};
#pragma unroll
    for (int t = 0; t < 4; t++) {
      float alv = al2[t * 16 + m], arv = ar2[t * 16 + m];
#pragma unroll
      for (int i = 0; i < 4; i++) { sl[i] += acc2[t][i] * alv; sr[i] += acc2[t][i] * arv; }
    }
#pragma unroll
    for (int o = 1; o < 16; o <<= 1)
#pragma unroll
      for (int i = 0; i < 4; i++) {
        sl[i] += __shfl_xor(sl[i], o, 64);
        sr[i] += __shfl_xor(sr[i], o, 64);
      }
    if (m == 0)
#pragma unroll
      for (int i = 0; i < 4; i++)
        fel[r0 + q * 4 + i] = make_float4(el1v[i], sl[i], sr[i], 0.f);
  }
  // y store: row = r0 + q*4 + i, col = t*16 + m (m89-verified layout)
#pragma unroll
  for (int t = 0; t < 4; t++)
#pragma unroll
    for (int i = 0; i < 4; i++)
      y[(size_t)(r0 + q * 4 + i) * 64 + t * 16 + m] = f32_to_bf16(acc2[t][i]);
}

// ---------------- mid aggregation: w = A1·y ; el2/er2 = A1·ey + c·a (scalars) ----------
__global__ __launch_bounds__(256) void agg_mid(const ushort_t* __restrict__ y,
                                               const float4* __restrict__ fel,
                                               const float* __restrict__ er,
                                               const int* __restrict__ cnt,
                                               const int* __restrict__ srcs,
                                               const float* __restrict__ cmeta,
                                               ushort_t* __restrict__ w,
                                               float* __restrict__ el2,
                                               float* __restrict__ er2) {
  int id = (threadIdx.x >> 6) * gridDim.x + blockIdx.x;  // gridDim%8==0: batch=XCD pairing
  int lane = threadIdx.x & 63;
  int g = lane >> 4, l16 = lane & 15;
  int b = id & 7, n = id >> 3;
  int deg = cnt[n]; if (deg > BUCKET) deg = BUCKET;
  int off0 = n * BUCKET;
  int rbase = b * N_NODES;
  float er_n = er[rbase + n];

  float acc[4] = {0.f, 0.f, 0.f, 0.f};
  float lsum = 0.f, sl2 = 0.f, sr2 = 0.f;

  for (int c = 0; c < deg; c += 64) {
    int j = c + lane;
    int s_my = 0;
    float w_my = 0.f;
    if (j < deg) {
      s_my = srcs[off0 + j];
      float4 fv = fel[rbase + s_my];        // (el1, ey_l, ey_r, -) one 16B gather
      float e = fv.x + er_n;
      e = e > 0.f ? e : NEG_SLOPE * e;
      w_my = __expf(e);                     // no max pass: |e|<=~10, shift-invariant
      lsum += w_my;
      sl2 += w_my * fv.y;
      sr2 += w_my * fv.z;
    }
    int cl = deg - c; if (cl > 64) cl = 64;
    for (int k0 = 0; k0 < cl; k0 += 16) {   // R5 4x-unrolled gather (MLP=4)
      float wk[4]; int sk[4];
#pragma unroll
      for (int u = 0; u < 4; u++) {
        int e_idx = k0 + u * 4 + g;
        wk[u] = __shfl(w_my, e_idx, 64);
        sk[u] = __shfl(s_my, e_idx, 64);
      }
      uint2 zw[4];
#pragma unroll
      for (int u = 0; u < 4; u++)
        zw[u] = *(const uint2*)(y + (size_t)(rbase + sk[u]) * 64 + l16 * 4);
#pragma unroll
      for (int u = 0; u < 4; u++) {
        acc[0] += wk[u] * bf16_to_f32((ushort_t)(zw[u].x & 0xFFFF));
        acc[1] += wk[u] * bf16_to_f32((ushort_t)(zw[u].x >> 16));
        acc[2] += wk[u] * bf16_to_f32((ushort_t)(zw[u].y & 0xFFFF));
        acc[3] += wk[u] * bf16_to_f32((ushort_t)(zw[u].y >> 16));
      }
    }
  }
#pragma unroll
  for (int j = 0; j < 4; j++) {
    acc[j] += __shfl_xor(acc[j], 16, 64);
    acc[j] += __shfl_xor(acc[j], 32, 64);
  }
  float sum = lsum;
#pragma unroll
  for (int o = 32; o; o >>= 1) {
    sum += __shfl_xor(sum, o, 64);
    sl2 += __shfl_xor(sl2, o, 64);
    sr2 += __shfl_xor(sr2, o, 64);
  }
  float inv = (deg > 0) ? 1.f / sum : 0.f;

  if (g == 0) {
    uint_t pk0 = (uint_t)f32_to_bf16(acc[0] * inv) | ((uint_t)f32_to_bf16(acc[1] * inv) << 16);
    uint_t pk1 = (uint_t)f32_to_bf16(acc[2] * inv) | ((uint_t)f32_to_bf16(acc[3] * inv) << 16);
    *(uint2*)(w + (size_t)(rbase + n) * 64 + l16 * 4) = make_uint2(pk0, pk1);
  }
  if (lane == 0) {
    el2[rbase + n] = sl2 * inv + cmeta[0];
    er2[rbase + n] = sr2 * inv + cmeta[1];
  }
}

// ---------------- final aggregation: o = A2·w + cb, row softmax -> fp32 out ----------
__global__ __launch_bounds__(256) void agg_fin(const ushort_t* __restrict__ w,
                                               const float* __restrict__ el,
                                               const float* __restrict__ er,
                                               const float* __restrict__ cb,
                                               const int* __restrict__ cnt,
                                               const int* __restrict__ srcs,
                                               float* __restrict__ outp) {
  int id = (threadIdx.x >> 6) * gridDim.x + blockIdx.x;
  int lane = threadIdx.x & 63;
  int g = lane >> 4, l16 = lane & 15;
  int b = id & 7, n = id >> 3;
  int deg = cnt[n]; if (deg > BUCKET) deg = BUCKET;
  int off0 = n * BUCKET;
  int rbase = b * N_NODES;
  float er_n = er[rbase + n];

  float acc[4] = {0.f, 0.f, 0.f, 0.f};
  float lsum = 0.f;

  for (int c = 0; c < deg; c += 64) {
    int j = c + lane;
    int s_my = 0;
    float w_my = 0.f;
    if (j < deg) {
      s_my = srcs[off0 + j];
      float e = el[rbase + s_my] + er_n;
      e = e > 0.f ? e : NEG_SLOPE * e;
      w_my = __expf(e);
      lsum += w_my;
    }
    int cl = deg - c; if (cl > 64) cl = 64;
    for (int k0 = 0; k0 < cl; k0 += 16) {
      float wk[4]; int sk[4];
#pragma unroll
      for (int u = 0; u < 4; u++) {
        int e_idx = k0 + u * 4 + g;
        wk[u] = __shfl(w_my, e_idx, 64);
        sk[u] = __shfl(s_my, e_idx, 64);
      }
      uint2 zw[4];
#pragma unroll
      for (int u = 0; u < 4; u++)
        zw[u] = *(const uint2*)(w + (size_t)(rbase + sk[u]) * 64 + l16 * 4);
#pragma unroll
      for (int u = 0; u < 4; u++) {
        acc[0] += wk[u] * bf16_to_f32((ushort_t)(zw[u].x & 0xFFFF));
        acc[1] += wk[u] * bf16_to_f32((ushort_t)(zw[u].x >> 16));
        acc[2] += wk[u] * bf16_to_f32((ushort_t)(zw[u].y & 0xFFFF));
        acc[3] += wk[u] * bf16_to_f32((ushort_t)(zw[u].y >> 16));
      }
    }
  }
#pragma unroll
  for (int j = 0; j < 4; j++) {
    acc[j] += __shfl_xor(acc[j], 16, 64);
    acc[j] += __shfl_xor(acc[j], 32, 64);
  }
  float sum = lsum;
#pragma unroll
  for (int o = 32; o; o >>= 1) sum += __shfl_xor(sum, o, 64);
  float inv = (deg > 0) ? 1.f / sum : 0.f;

  float o[4];
#pragma unroll
  for (int j = 0; j < 4; j++) o[j] = acc[j] * inv + cb[l16 * 4 + j];
  float mm = fmaxf(fmaxf(o[0], o[1]), fmaxf(o[2], o[3]));
#pragma unroll
  for (int d = 1; d < 16; d <<= 1) mm = fmaxf(mm, __shfl_xor(mm, d, 64));
  float p0 = __expf(o[0] - mm), p1 = __expf(o[1] - mm);
  float p2 = __expf(o[2] - mm), p3 = __expf(o[3] - mm);
  float ss = p0 + p1 + p2 + p3;
#pragma unroll
  for (int d = 1; d < 16; d <<= 1) ss += __shfl_xor(ss, d, 64);
  if (g == 0) {
    float issv = 1.f / ss;
    *(float4*)(outp + (size_t)(rbase + n) * 64 + l16 * 4) =
        make_float4(p0 * issv, p1 * issv, p2 * issv, p3 * issv);
  }
}

extern "C" void kernel_launch(void* const* d_in, const int* in_sizes, int n_in,
                              void* d_out, int out_size, void* d_ws, size_t ws_size,
                              hipStream_t stream) {
  const float* x   = (const float*)d_in[0];
  const float* W1  = (const float*)d_in[1];
  const float* al1 = (const float*)d_in[2];
  const float* ar1 = (const float*)d_in[3];
  const float* b1  = (const float*)d_in[4];
  const float* W2  = (const float*)d_in[5];
  const float* al2 = (const float*)d_in[6];
  const float* ar2 = (const float*)d_in[7];
  const float* b2  = (const float*)d_in[8];
  const int* src = (const int*)d_in[9];
  const int* dst = (const int*)d_in[10];

  char* base = (char*)d_ws;
  ushort_t* Bp1  = (ushort_t*)(base + OFF_BP1);
  ushort_t* Bp2  = (ushort_t*)(base + OFF_BP2);
  float*    cmeta= (float*)(base + OFF_CMETA);
  float*    cb   = (float*)(base + OFF_CB);
  float4*   fel  = (float4*)(base + OFF_FEL);
  ushort_t* y    = (ushort_t*)(base + OFF_Y);
  ushort_t* w    = (ushort_t*)(base + OFF_W);
  float* er1 = (float*)(base + OFF_ER1);
  float* el2 = (float*)(base + OFF_EL2);
  float* er2 = (float*)(base + OFF_ER2);
  int* cnt  = (int*)(base + OFF_CNT);
  int* srcs = (int*)(base + OFF_SRCS);

  // 1) setup: zero cnt + pack W1/W2 + cb/cmeta (proven R6 form)
  zero_pack_kernel<<<33, 256, 0, stream>>>(W1, W2, b1, b2, al2, ar2, cnt, Bp1, Bp2,
                                           cmeta, cb);

  // 2) fused GEMM: scatter + x@W1 -> LDS -> @W2 = y; er1 + fel=(el1,ey_l,ey_r)
  gemm_fused<<<M_ROWS / 64, 256, 0, stream>>>(x, Bp1, Bp2, al1, ar1, al2, ar2,
                                              er1, y, fel, src, dst, cnt, srcs);

  // 3) mid aggregation: w = A1·y ; el2/er2 (fel single-gather weight phase)
  agg_mid<<<M_ROWS / 4, 256, 0, stream>>>(y, fel, er1, cnt, srcs, cmeta, w, el2, er2);

  // 4) final aggregation + row softmax
  agg_fin<<<M_ROWS / 4, 256, 0, stream>>>(w, el2, er2, cb, cnt, srcs, (float*)d_out);
}

// Round 12
// 140.660 us; speedup vs baseline: 2.1364x; 1.0149x over previous
//
#include <hip/hip_runtime.h>
#include <hip/hip_bf16.h>

#define N_NODES 5000
#define N_EDGES 80000
#define HID_DIM 128
#define OUT_DIM 64
#define BATCH 8
#define M_ROWS 40000
#define NEG_SLOPE 0.2f
#define BUCKET 96   // fixed per-node capacity; deg~Poisson(16), P(>96)~0 (+20 sigma)

// R12: R11 (142.8us best) + step-8 gather chunks in both agg kernels.
// deg~Poisson(16): step-16 processes E[ceil(deg/16)*16]~23 edge-slots/unit (44%
// phantom); step-8 -> ~17.6 (10%). Per-group visit order (k0+4u+g, stride-4
// ascending) is IDENTICAL -> bitwise-same accumulation. MLP 4->2 costs <~1us
// (R5 calibration: full MLP 1->4 was only -3.1us at 32 waves/CU occupancy).
// Everything else byte-identical to R11.

typedef unsigned short ushort_t;
typedef unsigned int uint_t;
typedef __attribute__((ext_vector_type(8))) short short8;  // 8 bf16 = 4 VGPRs
typedef __attribute__((ext_vector_type(4))) float f32x4;

__device__ __forceinline__ float bf16_to_f32(ushort_t u) {
  return __uint_as_float(((uint_t)u) << 16);
}
__device__ __forceinline__ ushort_t f32_to_bf16(float f) {
  uint_t u = __float_as_uint(f);
  return (ushort_t)((u + 0x7FFF + ((u >> 16) & 1)) >> 16);  // RNE
}

// ws layout (R12 == R11)
#define OFF_BP1   0u          // 32 KB
#define OFF_BP2   32768u      // 16 KB
#define OFF_CMETA 49152u      // 2 floats (cl2, cr2)
#define OFF_CB    49184u      // 64 floats (c + b2)
#define OFF_FEL   65536u      // 40000 float4 (el1, ey_l, ey_r, pad) = 640 KB
#define OFF_Y     705536u     // 40000*64 bf16 = 5.12 MB
#define OFF_W     5825536u    // 40000*64 bf16 = 5.12 MB
#define OFF_ER1   10945536u   // 40000 floats
#define OFF_EL2   11105536u
#define OFF_ER2   11265536u
#define OFF_CNT   11425536u   // 5000 ints
#define OFF_SRCS  11445536u   // 5000*96 ints, ends 13,365,536

// ---------------- setup: zero cnt + pack W1/W2 + cb/cmeta (one dispatch, proven R6) -------
__global__ __launch_bounds__(256) void zero_pack_kernel(const float* __restrict__ W1,
                                                        const float* __restrict__ W2,
                                                        const float* __restrict__ b1,
                                                        const float* __restrict__ b2,
                                                        const float* __restrict__ al2,
                                                        const float* __restrict__ ar2,
                                                        int* __restrict__ cnt,
                                                        ushort_t* __restrict__ Bp1,
                                                        ushort_t* __restrict__ Bp2,
                                                        float* __restrict__ cmeta,
                                                        float* __restrict__ cb) {
  int bid = blockIdx.x;
  if (bid < 20) {
    int i = bid * 256 + threadIdx.x;
    if (i < N_NODES) cnt[i] = 0;
    return;
  }
  if (bid == 32) {
    int f = threadIdx.x;
    if (f < 64) {
      float c = 0.f;
#pragma unroll 8
      for (int k = 0; k < 128; k++) c += b1[k] * W2[(size_t)k * 64 + f];
      cb[f] = c + b2[f];
      float cl = c * al2[f], cr = c * ar2[f];
#pragma unroll
      for (int o = 32; o; o >>= 1) {
        cl += __shfl_xor(cl, o, 64);
        cr += __shfl_xor(cr, o, 64);
      }
      if (f == 0) { cmeta[0] = cl; cmeta[1] = cr; }
    }
    return;
  }
  int gid = (bid - 20) * 256 + threadIdx.x;  // 0..3071
  if (gid >= 3072) return;
  const float* W; ushort_t* Bp; int NC, idx;
  if (gid < 2048) { W = W1; Bp = Bp1; NC = 128; idx = gid; }
  else            { W = W2; Bp = Bp2; NC = 64;  idx = gid - 2048; }
  int l = idx & 63, tt = idx >> 6;
  int T = NC / 16;
  int kc = tt / T, t = tt % T;
  int col = t * 16 + (l & 15);
  int krow = kc * 32 + (l >> 4) * 8;
  short8 vv;
#pragma unroll
  for (int j = 0; j < 8; j++) vv[j] = (short)f32_to_bf16(W[(size_t)(krow + j) * NC + col]);
  *(short8*)(Bp + (size_t)idx * 8) = vv;
}

// ---------------- fused gemm: scatter + x@W1 (LDS) -> @W2 = y; fel pack epilogue ---------
__global__ __launch_bounds__(256) void gemm_fused(const float* __restrict__ A,
                                                  const ushort_t* __restrict__ Bp1,
                                                  const ushort_t* __restrict__ Bp2,
                                                  const float* __restrict__ al1,
                                                  const float* __restrict__ ar1,
                                                  const float* __restrict__ al2,
                                                  const float* __restrict__ ar2,
                                                  float* __restrict__ er1,
                                                  ushort_t* __restrict__ y,
                                                  float4* __restrict__ fel,
                                                  const int* __restrict__ e_src,
                                                  const int* __restrict__ e_dst,
                                                  int* __restrict__ cnt,
                                                  int* __restrict__ srcs) {
  // edge bucket-scatter prologue (gridDim=625 x 128 = 80000 exactly; proven form)
  if (threadIdx.x < 128) {
    int i = blockIdx.x * 128 + threadIdx.x;
    int d = e_dst[i];
    int pos = atomicAdd(&cnt[d], 1);
    if (pos < BUCKET) srcs[d * BUCKET + pos] = e_src[i];  // clamp: structurally safe
  }
  __shared__ ushort_t lds[64 * 128];  // 16 KB, z1 tile bf16, XOR-swizzled rows
  int wave = threadIdx.x >> 6, lane = threadIdx.x & 63;
  int q = lane >> 4, m = lane & 15;
  int r0 = blockIdx.x * 64 + wave * 16;

  // ---- stage 1: z1_tile = x_tile @ W1 (T=8) ----
  f32x4 acc[8];
#pragma unroll
  for (int t = 0; t < 8; t++)
#pragma unroll
    for (int i = 0; i < 4; i++) acc[t][i] = 0.f;
  const short8* B1 = (const short8*)Bp1;
  size_t arow = (size_t)(r0 + m) * 128;
#pragma unroll
  for (int kc = 0; kc < 4; kc++) {
    const float* Ap = A + arow + kc * 32 + q * 8;
    float4 v0 = *(const float4*)Ap;
    float4 v1 = *(const float4*)(Ap + 4);
    short8 af;
    af[0] = (short)f32_to_bf16(v0.x); af[1] = (short)f32_to_bf16(v0.y);
    af[2] = (short)f32_to_bf16(v0.z); af[3] = (short)f32_to_bf16(v0.w);
    af[4] = (short)f32_to_bf16(v1.x); af[5] = (short)f32_to_bf16(v1.y);
    af[6] = (short)f32_to_bf16(v1.z); af[7] = (short)f32_to_bf16(v1.w);
#pragma unroll
    for (int t = 0; t < 8; t++)
      acc[t] = __builtin_amdgcn_mfma_f32_16x16x32_bf16(af, B1[(kc * 8 + t) * 64 + lane], acc[t], 0, 0, 0);
  }
  // el1/er1 epilogue: keep el1 in regs for fel pack; store er1 (dense, per-node read)
  float el1v[4];
  {
    float sl[4] = {0.f, 0.f, 0.f, 0.f}, sr[4] = {0.f, 0.f, 0.f, 0.f};
#pragma unroll
    for (int t = 0; t < 8; t++) {
      float alv = al1[t * 16 + m], arv = ar1[t * 16 + m];
#pragma unroll
      for (int i = 0; i < 4; i++) { sl[i] += acc[t][i] * alv; sr[i] += acc[t][i] * arv; }
    }
#pragma unroll
    for (int o = 1; o < 16; o <<= 1)
#pragma unroll
      for (int i = 0; i < 4; i++) {
        sl[i] += __shfl_xor(sl[i], o, 64);
        sr[i] += __shfl_xor(sr[i], o, 64);
      }
#pragma unroll
    for (int i = 0; i < 4; i++) el1v[i] = sl[i];
    if (m == 0)
#pragma unroll
      for (int i = 0; i < 4; i++) er1[r0 + q * 4 + i] = sr[i];
  }
  // stage-1 -> LDS (bf16, RNE): row = q*4+i+wave*16, col = t*16+m; byte ^= (row&7)<<4
#pragma unroll
  for (int t = 0; t < 8; t++)
#pragma unroll
    for (int i = 0; i < 4; i++) {
      int row = q * 4 + i + wave * 16;
      int byte = row * 256 + (t * 16 + m) * 2;
      lds[(byte ^ ((row & 7) << 4)) >> 1] = f32_to_bf16(acc[t][i]);
    }
  __syncthreads();

  // ---- stage 2: y_tile = z1_tile(bf16) @ W2 (T=4) ----
  f32x4 acc2[4];
#pragma unroll
  for (int t = 0; t < 4; t++)
#pragma unroll
    for (int i = 0; i < 4; i++) acc2[t][i] = 0.f;
  const short8* B2 = (const short8*)Bp2;
  int row2 = wave * 16 + m;
#pragma unroll
  for (int kc = 0; kc < 4; kc++) {
    int byte = row2 * 256 + kc * 64 + q * 16;      // 16B-aligned; XOR keeps bits 0-3
    short8 af2 = *(const short8*)((const char*)lds + (byte ^ ((row2 & 7) << 4)));
#pragma unroll
    for (int t = 0; t < 4; t++)
      acc2[t] = __builtin_amdgcn_mfma_f32_16x16x32_bf16(af2, B2[(kc * 4 + t) * 64 + lane], acc2[t], 0, 0, 0);
  }
  // ey epilogue + fel pack: fel[row] = (el1, ey_l, ey_r, 0)
  {
    float sl[4] = {0.f, 0.f, 0.f, 0.f}, sr[4] = {0.f, 0.f, 0.f, 0.f};
#pragma unroll
    for (int t = 0; t < 4; t++) {
      float alv = al2[t * 16 + m], arv = ar2[t * 16 + m];
#pragma unroll
      for (int i = 0; i < 4; i++) { sl[i] += acc2[t][i] * alv; sr[i] += acc2[t][i] * arv; }
    }
#pragma unroll
    for (int o = 1; o < 16; o <<= 1)
#pragma unroll
      for (int i = 0; i < 4; i++) {
        sl[i] += __shfl_xor(sl[i], o, 64);
        sr[i] += __shfl_xor(sr[i], o, 64);
      }
    if (m == 0)
#pragma unroll
      for (int i = 0; i < 4; i++)
        fel[r0 + q * 4 + i] = make_float4(el1v[i], sl[i], sr[i], 0.f);
  }
  // y store: row = r0 + q*4 + i, col = t*16 + m (m89-verified layout)
#pragma unroll
  for (int t = 0; t < 4; t++)
#pragma unroll
    for (int i = 0; i < 4; i++)
      y[(size_t)(r0 + q * 4 + i) * 64 + t * 16 + m] = f32_to_bf16(acc2[t][i]);
}

// ---------------- mid aggregation: w = A1·y ; el2/er2 = A1·ey + c·a (scalars) ----------
__global__ __launch_bounds__(256) void agg_mid(const ushort_t* __restrict__ y,
                                               const float4* __restrict__ fel,
                                               const float* __restrict__ er,
                                               const int* __restrict__ cnt,
                                               const int* __restrict__ srcs,
                                               const float* __restrict__ cmeta,
                                               ushort_t* __restrict__ w,
                                               float* __restrict__ el2,
                                               float* __restrict__ er2) {
  int id = (threadIdx.x >> 6) * gridDim.x + blockIdx.x;  // gridDim%8==0: batch=XCD pairing
  int lane = threadIdx.x & 63;
  int g = lane >> 4, l16 = lane & 15;
  int b = id & 7, n = id >> 3;
  int deg = cnt[n]; if (deg > BUCKET) deg = BUCKET;
  int off0 = n * BUCKET;
  int rbase = b * N_NODES;
  float er_n = er[rbase + n];

  float acc[4] = {0.f, 0.f, 0.f, 0.f};
  float lsum = 0.f, sl2 = 0.f, sr2 = 0.f;

  for (int c = 0; c < deg; c += 64) {
    int j = c + lane;
    int s_my = 0;
    float w_my = 0.f;
    if (j < deg) {
      s_my = srcs[off0 + j];
      float4 fv = fel[rbase + s_my];        // (el1, ey_l, ey_r, -) one 16B gather
      float e = fv.x + er_n;
      e = e > 0.f ? e : NEG_SLOPE * e;
      w_my = __expf(e);                     // no max pass: |e|<=~10, shift-invariant
      lsum += w_my;
      sl2 += w_my * fv.y;
      sr2 += w_my * fv.z;
    }
    int cl = deg - c; if (cl > 64) cl = 64;
    // R12: step-8 chunks (2-deep MLP). Visit order per group = k0+4u+g, stride-4
    // ascending — identical to step-16 — accumulation bitwise unchanged.
    for (int k0 = 0; k0 < cl; k0 += 8) {
      float wk[2]; int sk[2];
#pragma unroll
      for (int u = 0; u < 2; u++) {
        int e_idx = k0 + u * 4 + g;
        wk[u] = __shfl(w_my, e_idx, 64);
        sk[u] = __shfl(s_my, e_idx, 64);
      }
      uint2 zw[2];
#pragma unroll
      for (int u = 0; u < 2; u++)
        zw[u] = *(const uint2*)(y + (size_t)(rbase + sk[u]) * 64 + l16 * 4);
#pragma unroll
      for (int u = 0; u < 2; u++) {
        acc[0] += wk[u] * bf16_to_f32((ushort_t)(zw[u].x & 0xFFFF));
        acc[1] += wk[u] * bf16_to_f32((ushort_t)(zw[u].x >> 16));
        acc[2] += wk[u] * bf16_to_f32((ushort_t)(zw[u].y & 0xFFFF));
        acc[3] += wk[u] * bf16_to_f32((ushort_t)(zw[u].y >> 16));
      }
    }
  }
#pragma unroll
  for (int j = 0; j < 4; j++) {
    acc[j] += __shfl_xor(acc[j], 16, 64);
    acc[j] += __shfl_xor(acc[j], 32, 64);
  }
  float sum = lsum;
#pragma unroll
  for (int o = 32; o; o >>= 1) {
    sum += __shfl_xor(sum, o, 64);
    sl2 += __shfl_xor(sl2, o, 64);
    sr2 += __shfl_xor(sr2, o, 64);
  }
  float inv = (deg > 0) ? 1.f / sum : 0.f;

  if (g == 0) {
    uint_t pk0 = (uint_t)f32_to_bf16(acc[0] * inv) | ((uint_t)f32_to_bf16(acc[1] * inv) << 16);
    uint_t pk1 = (uint_t)f32_to_bf16(acc[2] * inv) | ((uint_t)f32_to_bf16(acc[3] * inv) << 16);
    *(uint2*)(w + (size_t)(rbase + n) * 64 + l16 * 4) = make_uint2(pk0, pk1);
  }
  if (lane == 0) {
    el2[rbase + n] = sl2 * inv + cmeta[0];
    er2[rbase + n] = sr2 * inv + cmeta[1];
  }
}

// ---------------- final aggregation: o = A2·w + cb, row softmax -> fp32 out ----------
__global__ __launch_bounds__(256) void agg_fin(const ushort_t* __restrict__ w,
                                               const float* __restrict__ el,
                                               const float* __restrict__ er,
                                               const float* __restrict__ cb,
                                               const int* __restrict__ cnt,
                                               const int* __restrict__ srcs,
                                               float* __restrict__ outp) {
  int id = (threadIdx.x >> 6) * gridDim.x + blockIdx.x;
  int lane = threadIdx.x & 63;
  int g = lane >> 4, l16 = lane & 15;
  int b = id & 7, n = id >> 3;
  int deg = cnt[n]; if (deg > BUCKET) deg = BUCKET;
  int off0 = n * BUCKET;
  int rbase = b * N_NODES;
  float er_n = er[rbase + n];

  float acc[4] = {0.f, 0.f, 0.f, 0.f};
  float lsum = 0.f;

  for (int c = 0; c < deg; c += 64) {
    int j = c + lane;
    int s_my = 0;
    float w_my = 0.f;
    if (j < deg) {
      s_my = srcs[off0 + j];
      float e = el[rbase + s_my] + er_n;
      e = e > 0.f ? e : NEG_SLOPE * e;
      w_my = __expf(e);
      lsum += w_my;
    }
    int cl = deg - c; if (cl > 64) cl = 64;
    // R12: step-8 chunks (2-deep MLP), bitwise-same visit order as step-16
    for (int k0 = 0; k0 < cl; k0 += 8) {
      float wk[2]; int sk[2];
#pragma unroll
      for (int u = 0; u < 2; u++) {
        int e_idx = k0 + u * 4 + g;
        wk[u] = __shfl(w_my, e_idx, 64);
        sk[u] = __shfl(s_my, e_idx, 64);
      }
      uint2 zw[2];
#pragma unroll
      for (int u = 0; u < 2; u++)
        zw[u] = *(const uint2*)(w + (size_t)(rbase + sk[u]) * 64 + l16 * 4);
#pragma unroll
      for (int u = 0; u < 2; u++) {
        acc[0] += wk[u] * bf16_to_f32((ushort_t)(zw[u].x & 0xFFFF));
        acc[1] += wk[u] * bf16_to_f32((ushort_t)(zw[u].x >> 16));
        acc[2] += wk[u] * bf16_to_f32((ushort_t)(zw[u].y & 0xFFFF));
        acc[3] += wk[u] * bf16_to_f32((ushort_t)(zw[u].y >> 16));
      }
    }
  }
#pragma unroll
  for (int j = 0; j < 4; j++) {
    acc[j] += __shfl_xor(acc[j], 16, 64);
    acc[j] += __shfl_xor(acc[j], 32, 64);
  }
  float sum = lsum;
#pragma unroll
  for (int o = 32; o; o >>= 1) sum += __shfl_xor(sum, o, 64);
  float inv = (deg > 0) ? 1.f / sum : 0.f;

  float o[4];
#pragma unroll
  for (int j = 0; j < 4; j++) o[j] = acc[j] * inv + cb[l16 * 4 + j];
  float mm = fmaxf(fmaxf(o[0], o[1]), fmaxf(o[2], o[3]));
#pragma unroll
  for (int d = 1; d < 16; d <<= 1) mm = fmaxf(mm, __shfl_xor(mm, d, 64));
  float p0 = __expf(o[0] - mm), p1 = __expf(o[1] - mm);
  float p2 = __expf(o[2] - mm), p3 = __expf(o[3] - mm);
  float ss = p0 + p1 + p2 + p3;
#pragma unroll
  for (int d = 1; d < 16; d <<= 1) ss += __shfl_xor(ss, d, 64);
  if (g == 0) {
    float issv = 1.f / ss;
    *(float4*)(outp + (size_t)(rbase + n) * 64 + l16 * 4) =
        make_float4(p0 * issv, p1 * issv, p2 * issv, p3 * issv);
  }
}

extern "C" void kernel_launch(void* const* d_in, const int* in_sizes, int n_in,
                              void* d_out, int out_size, void* d_ws, size_t ws_size,
                              hipStream_t stream) {
  const float* x   = (const float*)d_in[0];
  const float* W1  = (const float*)d_in[1];
  const float* al1 = (const float*)d_in[2];
  const float* ar1 = (const float*)d_in[3];
  const float* b1  = (const float*)d_in[4];
  const float* W2  = (const float*)d_in[5];
  const float* al2 = (const float*)d_in[6];
  const float* ar2 = (const float*)d_in[7];
  const float* b2  = (const float*)d_in[8];
  const int* src = (const int*)d_in[9];
  const int* dst = (const int*)d_in[10];

  char* base = (char*)d_ws;
  ushort_t* Bp1  = (ushort_t*)(base + OFF_BP1);
  ushort_t* Bp2  = (ushort_t*)(base + OFF_BP2);
  float*    cmeta= (float*)(base + OFF_CMETA);
  float*    cb   = (float*)(base + OFF_CB);
  float4*   fel  = (float4*)(base + OFF_FEL);
  ushort_t* y    = (ushort_t*)(base + OFF_Y);
  ushort_t* w    = (ushort_t*)(base + OFF_W);
  float* er1 = (float*)(base + OFF_ER1);
  float* el2 = (float*)(base + OFF_EL2);
  float* er2 = (float*)(base + OFF_ER2);
  int* cnt  = (int*)(base + OFF_CNT);
  int* srcs = (int*)(base + OFF_SRCS);

  // 1) setup: zero cnt + pack W1/W2 + cb/cmeta (proven R6 form)
  zero_pack_kernel<<<33, 256, 0, stream>>>(W1, W2, b1, b2, al2, ar2, cnt, Bp1, Bp2,
                                           cmeta, cb);

  // 2) fused GEMM: scatter + x@W1 -> LDS -> @W2 = y; er1 + fel=(el1,ey_l,ey_r)
  gemm_fused<<<M_ROWS / 64, 256, 0, stream>>>(x, Bp1, Bp2, al1, ar1, al2, ar2,
                                              er1, y, fel, src, dst, cnt, srcs);

  // 3) mid aggregation: w = A1·y ; el2/er2 (fel single-gather weight phase)
  agg_mid<<<M_ROWS / 4, 256, 0, stream>>>(y, fel, er1, cnt, srcs, cmeta, w, el2, er2);

  // 4) final aggregation + row softmax
  agg_fin<<<M_ROWS / 4, 256, 0, stream>>>(w, el2, er2, cb, cnt, srcs, (float*)d_out);
}